// Round 6
// baseline (1214.402 us; speedup 1.0000x reference)
//
#include <hip/hip_runtime.h>

#define T_ 512
#define B_ 256
#define H_ 256
#define DIN_ 64

typedef __attribute__((ext_vector_type(8))) short short8;
typedef __attribute__((ext_vector_type(4))) float f32x4;
typedef __attribute__((ext_vector_type(4))) unsigned int u32x4;

__device__ __forceinline__ unsigned short f2bf(float f) {
  unsigned u = __float_as_uint(f);
  u += 0x7FFFu + ((u >> 16) & 1u);   // RNE
  return (unsigned short)(u >> 16);
}
__device__ __forceinline__ float bf2f(unsigned short s) {
  return __uint_as_float(((unsigned)s) << 16);
}
__device__ __forceinline__ float sigm(float x) { return 1.0f / (1.0f + __expf(-x)); }
__device__ __forceinline__ float tanh_(float x) {
  float xx = fminf(fmaxf(x, -30.0f), 30.0f);
  float e = __expf(2.0f * xx);
  return (e - 1.0f) / (e + 1.0f);
}

// sc1 (agent-scope) loads: bypass L1/L2, read LLC-fresh data. R2/R5-proven.
__device__ __forceinline__ void load16_sc1(const unsigned* p, u32x4& a,
                                           u32x4& b, u32x4& c, u32x4& d) {
  asm volatile(
      "global_load_dwordx4 %0, %4, off sc1\n\t"
      "global_load_dwordx4 %1, %4, off offset:16 sc1\n\t"
      "global_load_dwordx4 %2, %4, off offset:32 sc1\n\t"
      "global_load_dwordx4 %3, %4, off offset:48 sc1\n\t"
      "s_waitcnt vmcnt(0)"
      : "=v"(a), "=v"(b), "=v"(c), "=v"(d)
      : "v"(p) : "memory");
}

__device__ __forceinline__ bool tags_ok(u32x4 a, u32x4 b, u32x4 c, u32x4 d,
                                        unsigned w) {
  unsigned m = (a.x >> 16) ^ w; m |= (a.y >> 16) ^ w;
  m |= (a.z >> 16) ^ w;         m |= (a.w >> 16) ^ w;
  m |= (b.x >> 16) ^ w;         m |= (b.y >> 16) ^ w;
  m |= (b.z >> 16) ^ w;         m |= (b.w >> 16) ^ w;
  m |= (c.x >> 16) ^ w;         m |= (c.y >> 16) ^ w;
  m |= (c.z >> 16) ^ w;         m |= (c.w >> 16) ^ w;
  m |= (d.x >> 16) ^ w;         m |= (d.y >> 16) ^ w;
  m |= (d.z >> 16) ^ w;         m |= (d.w >> 16) ^ w;
  return m == 0;
}

// R6: one barrier per step. Wave w computes ALL 4 gates for h-cols
// [gc*16+w*4, +4): MFMA n = g*4+q maps to W row j = g*256 + gc*16 + w*4 + q.
// After MFMA, an in-register 4x4 transpose (lane bits 2-3 <-> acc-reg bits,
// shfl_xor masks 4/8) gives each lane all 4 gates of one (row,col) element;
// cell update + fire-and-forget tagged sc1 store issue per-wave with NO
// second barrier and no gbuf. h_s/x_s are parity double-buffered so the
// single barrier (after staging) is sufficient: a wave can stage s+1 into
// parity p^1 while a peer still reads parity p; it cannot reuse p before
// the s+1 barrier, which requires all waves done with p.
// Clobber-safety of hbuf (unchanged from R5): wave stores tag s+1 only after
// its wg fully acquired s; peers published s only after fully acquiring s-1;
// so all readers of a slot finish before it is overwritten.
__global__ __launch_bounds__(256) void lstm_kern(
    const float* __restrict__ xin, const float* __restrict__ h0f,
    const float* __restrict__ c0f, const float* __restrict__ Wih,
    const float* __restrict__ Whh, const float* __restrict__ bias,
    const float* __restrict__ Wout, const float* __restrict__ bout,
    float* __restrict__ out, unsigned* hbuf32)
{
  const int tid = threadIdx.x;
  const int gb  = blockIdx.x >> 4;
  const int gc  = blockIdx.x & 15;
  const int wv  = tid >> 6;
  const int ln  = tid & 63;
  const int colB = ln & 15;   // MFMA n
  const int krow = ln >> 4;   // MFMA k-quad

  __shared__ unsigned short h_s[2][16 * 264];  // parity-double-buffered
  __shared__ unsigned short x_s[2][16 * 72];

  // ---- W fragments, gate-interleaved N mapping: n=g*4+q -> row g*256+... ----
  const int gg = colB >> 2, qq = colB & 3;
  const int j = gg * H_ + gc * 16 + wv * 4 + qq;   // row in [0,4H)
  short8 bh[8], bx[2];
  #pragma unroll
  for (int kc = 0; kc < 8; ++kc) {
    const float* p = Whh + j * H_ + kc * 32 + krow * 8;
    short8 f;
    #pragma unroll
    for (int i = 0; i < 8; ++i) f[i] = (short)f2bf(p[i]);
    bh[kc] = f;
  }
  #pragma unroll
  for (int kc = 0; kc < 2; ++kc) {
    const float* p = Wih + j * DIN_ + kc * 32 + krow * 8;
    short8 f;
    #pragma unroll
    for (int i = 0; i < 8; ++i) f[i] = (short)f2bf(p[i]);
    bx[kc] = f;
  }
  const float bval = bias[j];

  // element owned after transpose: row quad*4 + r_lo, col gc*16 + wv*4 + q
  const int quad = ln >> 4;
  const int r_lo = (ln >> 2) & 3;
  const int q    = ln & 3;
  const int erow = quad * 4 + r_lo;          // row in group (0..15)
  const int grow = gb * 16 + erow;           // global batch row
  const int gcol = gc * 16 + wv * 4 + q;     // global h col
  float c_val = c0f[grow * H_ + gcol];
  float h_val = 0.0f;

  // hbuf32[2 parity][16 groups][16 rows][256 cols] dwords
  const int hr = tid >> 4;            // consumer row
  const int hcb = (tid & 15) * 16;    // consumer col base (16 dwords)
  const unsigned* ldp_base = hbuf32 + gb * 4096 + hr * 256 + hcb;
  unsigned* stp_base = hbuf32 + gb * 4096 + erow * 256 + gcol;

  const float* xrow = xin + ((gb * 16 + (tid >> 4)) * T_) * DIN_ + (tid & 15) * 4;

  for (int s = 1; s <= T_; ++s) {
    const int p = (s - 1) & 1;   // LDS parity for this step's operands
    // ---- stage x_{s-1} -> LDS bf16 (1 float4/thread) ----
    {
      float4 v = *(const float4*)(xrow + (s - 1) * DIN_);
      unsigned short* qp = &x_s[p][(tid >> 4) * 72 + (tid & 15) * 4];
      qp[0] = f2bf(v.x); qp[1] = f2bf(v.y); qp[2] = f2bf(v.z); qp[3] = f2bf(v.w);
    }
    // ---- acquire h^(s-1): tag-validated sc1 loads (the load IS the poll) ----
    if (s == 1) {
      #pragma unroll
      for (int it = 0; it < 4; ++it) {
        int e4 = tid + it * 256;
        int r = e4 >> 6, c4 = e4 & 63;
        float4 v = *((const float4*)(h0f + (gb * 16 + r) * H_) + c4);
        unsigned short* qp = &h_s[p][r * 264 + c4 * 4];
        qp[0] = f2bf(v.x); qp[1] = f2bf(v.y); qp[2] = f2bf(v.z); qp[3] = f2bf(v.w);
      }
    } else {
      const unsigned want = (unsigned)(s - 1);
      const unsigned* ldp = ldp_base + (((s - 1) & 1) << 16);
      u32x4 va, vb, vc, vd;
      int tries = 0;
      do {
        load16_sc1(ldp, va, vb, vc, vd);
        if (tags_ok(va, vb, vc, vd, want)) break;
      } while (++tries < (1 << 18));
      unsigned* q32 = (unsigned*)&h_s[p][hr * 264 + hcb];
      q32[0] = (va.x & 0xFFFFu) | (va.y << 16);
      q32[1] = (va.z & 0xFFFFu) | (va.w << 16);
      q32[2] = (vb.x & 0xFFFFu) | (vb.y << 16);
      q32[3] = (vb.z & 0xFFFFu) | (vb.w << 16);
      q32[4] = (vc.x & 0xFFFFu) | (vc.y << 16);
      q32[5] = (vc.z & 0xFFFFu) | (vc.w << 16);
      q32[6] = (vd.x & 0xFFFFu) | (vd.y << 16);
      q32[7] = (vd.z & 0xFFFFu) | (vd.w << 16);
    }
    __syncthreads();   // the ONLY barrier per step

    // ---- gates: K = 64 (x) + 256 (h), n = gate-interleaved ----
    f32x4 acc = {0.f, 0.f, 0.f, 0.f};
    #pragma unroll
    for (int kc = 0; kc < 2; ++kc) {
      short8 a = *(const short8*)&x_s[p][colB * 72 + kc * 32 + krow * 8];
      acc = __builtin_amdgcn_mfma_f32_16x16x32_bf16(a, bx[kc], acc, 0, 0, 0);
    }
    #pragma unroll
    for (int kc = 0; kc < 8; ++kc) {
      short8 a = *(const short8*)&h_s[p][colB * 264 + kc * 32 + krow * 8];
      acc = __builtin_amdgcn_mfma_f32_16x16x32_bf16(a, bh[kc], acc, 0, 0, 0);
    }

    // ---- in-wave 4x4 transpose: lane bits 2-3 (gate) <-> reg bits (row) ----
    float v0 = acc[0] + bval, v1 = acc[1] + bval,
          v2 = acc[2] + bval, v3 = acc[3] + bval;
    {
      int g0 = (ln >> 2) & 1;
      float s0 = g0 ? v0 : v1, s1 = g0 ? v2 : v3;
      float t0 = __shfl_xor(s0, 4, 64), t1 = __shfl_xor(s1, 4, 64);
      if (g0) { v0 = t0; v2 = t1; } else { v1 = t0; v3 = t1; }
    }
    {
      int g1 = (ln >> 3) & 1;
      float s0 = g1 ? v0 : v2, s1 = g1 ? v1 : v3;
      float t0 = __shfl_xor(s0, 8, 64), t1 = __shfl_xor(s1, 8, 64);
      if (g1) { v0 = t0; v1 = t1; } else { v2 = t0; v3 = t1; }
    }
    // v0..v3 = gates i,f,g,o for element (erow, gcol)

    // ---- cell update + fire-and-forget tagged store (no barrier!) ----
    c_val = sigm(v1) * c_val + sigm(v0) * tanh_(v2);
    h_val = sigm(v3) * tanh_(c_val);
    unsigned pk = ((unsigned)s << 16) | (unsigned)f2bf(h_val);
    __hip_atomic_store(stp_base + ((s & 1) << 16), pk,
                       __ATOMIC_RELAXED, __HIP_MEMORY_SCOPE_AGENT);
  }

  // ---- outputs: rnn_outputs | logits | h | c ----
  out[grow * H_ + gcol] = h_val;                 // out0: rnn_outputs
  out[67584 + grow * H_ + gcol] = h_val;         // out2: h   (65536+2048)
  out[133120 + grow * H_ + gcol] = c_val;        // out3: c

  if (gc == 0) {  // logits for this batch group: need full h^T rows
    const unsigned want = (unsigned)T_;
    const unsigned* ldp = ldp_base + ((T_ & 1) << 16);
    u32x4 va, vb, vc, vd;
    int tries = 0;
    do {
      load16_sc1(ldp, va, vb, vc, vd);
      if (tags_ok(va, vb, vc, vd, want)) break;
    } while (++tries < (1 << 18));
    // stage into parity-0 LDS buffer (last step used parity 1 -> no conflict)
    unsigned* q32 = (unsigned*)&h_s[0][hr * 264 + hcb];
    q32[0] = (va.x & 0xFFFFu) | (va.y << 16);
    q32[1] = (va.z & 0xFFFFu) | (va.w << 16);
    q32[2] = (vb.x & 0xFFFFu) | (vb.y << 16);
    q32[3] = (vb.z & 0xFFFFu) | (vb.w << 16);
    q32[4] = (vc.x & 0xFFFFu) | (vc.y << 16);
    q32[5] = (vc.z & 0xFFFFu) | (vc.w << 16);
    q32[6] = (vd.x & 0xFFFFu) | (vd.y << 16);
    q32[7] = (vd.z & 0xFFFFu) | (vd.w << 16);
    __syncthreads();
    if (tid < 128) {
      int r = tid >> 3, o = tid & 7;
      float a = bout[o];
      for (int k = 0; k < H_; ++k)
        a = fmaf(bf2f(h_s[0][r * 264 + k]), Wout[o * H_ + k], a);
      out[65536 + (gb * 16 + r) * 8 + o] = a;   // out1: logits
    }
  }
}

extern "C" void kernel_launch(void* const* d_in, const int* in_sizes, int n_in,
                              void* d_out, int out_size, void* d_ws, size_t ws_size,
                              hipStream_t stream) {
  const float* xin  = (const float*)d_in[0];
  const float* h0f  = (const float*)d_in[1];
  const float* c0f  = (const float*)d_in[2];
  const float* Wih  = (const float*)d_in[3];
  const float* Whh  = (const float*)d_in[4];
  const float* bias = (const float*)d_in[5];
  const float* Wout = (const float*)d_in[6];
  const float* bout = (const float*)d_in[7];
  float* out = (float*)d_out;

  // ws: hbuf32[2][16][16][256] dwords (512 KiB)
  unsigned* hbuf32 = (unsigned*)d_ws;

  void* args[] = {&xin, &h0f, &c0f, &Wih, &Whh, &bias, &Wout, &bout,
                  &out, &hbuf32};
  hipLaunchCooperativeKernel((void*)lstm_kern, dim3(256), dim3(256),
                             args, 0, stream);
}